// Round 2
// baseline (433.382 us; speedup 1.0000x reference)
//
#include <hip/hip_runtime.h>
#include <hip/hip_bf16.h>
#include <stdint.h>

#define T_TOK 4096
#define DD 1024
#define EE 8
#define CC 512
#define FF 2752
#define FP 2816

typedef __attribute__((ext_vector_type(8))) short bf16x8;
typedef __attribute__((ext_vector_type(4))) float f32x4;
typedef __attribute__((ext_vector_type(4))) unsigned short us4;

__device__ __forceinline__ float bf2f(unsigned short u) {
  union { float f; unsigned int i; } v; v.i = ((unsigned int)u) << 16; return v.f;
}
__device__ __forceinline__ unsigned short f2bf(float f) {
  union { float f; unsigned int i; } v; v.f = f;
  unsigned int r = v.i + 0x7fffu + ((v.i >> 16) & 1u);
  return (unsigned short)(r >> 16);
}

#define GLDS16(g, l) __builtin_amdgcn_global_load_lds( \
    (const __attribute__((address_space(1))) void*)(g), \
    (__attribute__((address_space(3))) void*)(l), 16, 0, 0)

// ---------------- weight transpose + f32->bf16 -------------------
// in: [R][C] f32 (row pitch C). out: [C][R] bf16. 64x64 tiles, exact.
__global__ __launch_bounds__(256)
void transpose_k(const float* __restrict__ in, unsigned short* __restrict__ out,
                 int R, int C, long inStride, long outStride) {
  __shared__ unsigned short sm[64][68];
  int b = blockIdx.z;
  in += (long)b * inStride;
  out += (long)b * outStride;
  int cb = blockIdx.x * 64, rb = blockIdx.y * 64;
  int t = threadIdx.x;
  int rr = t >> 4, c4 = (t & 15) * 4;
#pragma unroll
  for (int i = 0; i < 4; ++i) {
    int r = rr + i * 16;
    float4 v = *(const float4*)(in + (long)(rb + r) * C + cb + c4);
    us4 o; o.x = f2bf(v.x); o.y = f2bf(v.y); o.z = f2bf(v.z); o.w = f2bf(v.w);
    *(us4*)&sm[r][c4] = o;
  }
  __syncthreads();
  int r4 = (t & 15) * 4, cc = t >> 4;
#pragma unroll
  for (int i = 0; i < 4; ++i) {
    int c = cc + i * 16;
    us4 o;
    o.x = sm[r4 + 0][c]; o.y = sm[r4 + 1][c];
    o.z = sm[r4 + 2][c]; o.w = sm[r4 + 3][c];
    *(us4*)(out + (long)(cb + c) * R + rb + r4) = o;
  }
}

__global__ void zero_me_k(float* me) { if (threadIdx.x < EE) me[threadIdx.x] = 0.0f; }

// ---------------- gating ----------------
__global__ void gate_k(const float* __restrict__ x, const float* __restrict__ wg,
                       const float* __restrict__ cw, const float* __restrict__ cbv,
                       int* __restrict__ idx, float* __restrict__ gatev,
                       float* __restrict__ coef, float* __restrict__ me_sum) {
  int tid = threadIdx.x, lane = tid & 63, wv = tid >> 6;
  int t = blockIdx.x * 4 + wv;
  const float* xr = x + (long)t * DD;
  float acc[EE] = {0,0,0,0,0,0,0,0};
  float c0 = 0.0f, c1 = 0.0f;
  for (int d = lane; d < DD; d += 64) {
    float xv = xr[d];
#pragma unroll
    for (int e = 0; e < EE; ++e) acc[e] += xv * wg[d * EE + e];
    c0 += xv * cw[d * 2 + 0];
    c1 += xv * cw[d * 2 + 1];
  }
#pragma unroll
  for (int o = 32; o > 0; o >>= 1) {
#pragma unroll
    for (int e = 0; e < EE; ++e) acc[e] += __shfl_xor(acc[e], o);
    c0 += __shfl_xor(c0, o);
    c1 += __shfl_xor(c1, o);
  }
  __shared__ float sme[EE];
  if (tid < EE) sme[tid] = 0.0f;
  __syncthreads();
  if (lane == 0) {
    float m = acc[0]; int am = 0;
#pragma unroll
    for (int e = 1; e < EE; ++e) if (acc[e] > m) { m = acc[e]; am = e; }
    float g[EE]; float s = 0.0f;
#pragma unroll
    for (int e = 0; e < EE; ++e) { g[e] = __expf(acc[e] - m); s += g[e]; }
    float inv = 1.0f / s;
    idx[t] = am;
    gatev[t] = g[am] * inv;
#pragma unroll
    for (int e = 0; e < EE; ++e) atomicAdd(&sme[e], g[e] * inv);
    float l0 = c0 + cbv[0], l1 = c1 + cbv[1];
    float mm = fmaxf(l0, l1);
    float e0 = __expf(l0 - mm), e1 = __expf(l1 - mm);
    float is = 1.0f / (e0 + e1);
    coef[t * 2 + 0] = e0 * is;
    coef[t * 2 + 1] = e1 * is;
  }
  __syncthreads();
  if (tid < EE) atomicAdd(&me_sum[tid], sme[tid]);
}

// ---------------- capacity scan ----------------
__global__ void scan_k(const int* __restrict__ idx, const float* __restrict__ me_sum,
                       int* __restrict__ slot, int* __restrict__ tok,
                       float* __restrict__ out_tail) {
  __shared__ int sidx[T_TOK];
  __shared__ int counts[EE];
  int tid = threadIdx.x;
  for (int i = tid; i < T_TOK; i += 512) sidx[i] = idx[i];
  __syncthreads();
  int e = tid >> 6, lane = tid & 63;
  int base = 0;
  for (int it = 0; it < T_TOK / 64; ++it) {
    int t = it * 64 + lane;
    bool f = (sidx[t] == e);
    unsigned long long m = __ballot(f);
    if (f) {
      int loc = base + __popcll(m & ((1ull << lane) - 1ull));
      slot[t] = (loc < CC) ? loc : -1;
      if (loc < CC) tok[e * CC + loc] = t;
    }
    base += __popcll(m);
  }
  if (lane == 0) counts[e] = base;
  __syncthreads();
  int filled = min(counts[e], CC);
  for (int c = filled + lane; c < CC; c += 64) tok[e * CC + c] = -1;
  if (tid == 0) {
    float la = 0.0f;
    for (int i = 0; i < EE; ++i) la += me_sum[i] * (float)counts[i];
    la *= (float)EE / ((float)T_TOK * (float)T_TOK);
    out_tail[0] = la;
    for (int i = 0; i < EE; ++i) out_tail[1 + i] = (float)counts[i];
  }
}

// ---------------- gather + bf16 convert ----------------
__global__ void gather_k(const float* __restrict__ x, const int* __restrict__ tok,
                         unsigned short* __restrict__ xb, unsigned short* __restrict__ xe) {
  int r = blockIdx.x, tid = threadIdx.x;
  int d = tid * 4;
  if (r < T_TOK) {
    float4 v = *(const float4*)(x + (long)r * DD + d);
    us4 o; o.x = f2bf(v.x); o.y = f2bf(v.y); o.z = f2bf(v.z); o.w = f2bf(v.w);
    *(us4*)(xb + (long)r * DD + d) = o;
  } else {
    int s = r - T_TOK;
    int t = tok[s];
    us4 o = {0, 0, 0, 0};
    if (t >= 0) {
      float4 v = *(const float4*)(x + (long)t * DD + d);
      o.x = f2bf(v.x); o.y = f2bf(v.y); o.z = f2bf(v.z); o.w = f2bf(v.w);
    }
    *(us4*)(xe + (long)s * DD + d) = o;
  }
}

// ---------------- GEMM1: H = silu(A@W1)*(A@W3) -------------------
// 128x64(x2) tile, BK=32, 4 waves, fragment-ordered LDS staging.
__global__ __launch_bounds__(256)
void gemm1_k(const unsigned short* __restrict__ xe, const unsigned short* __restrict__ xb,
             const unsigned short* __restrict__ w1t, const unsigned short* __restrict__ w3t,
             const unsigned short* __restrict__ rw1t, const unsigned short* __restrict__ rw3t,
             unsigned short* __restrict__ He, unsigned short* __restrict__ Hr) {
  // XCD-chunked work mapping: 2752 blocks, 344 per XCD.
  int lin = blockIdx.x;
  int work = (lin & 7) * 344 + (lin >> 3);
  const unsigned short *A, *B1, *B3;
  unsigned short* H;
  int nt;
  if (work < 1376) {               // experts: ((e*43 + nt)*4 + mt)
    int mt = work & 3;
    int q = work >> 2;
    nt = q % 43;
    int e = q / 43;
    A = xe + (size_t)(e * 4 + mt) * 128 * DD;
    B1 = w1t + (size_t)e * FP * DD;
    B3 = w3t + (size_t)e * FP * DD;
    H = He + (size_t)(e * 4 + mt) * 128 * FF;
  } else {                         // residual: nt*32 + mt
    int q = work - 1376;
    int mt = q & 31;
    nt = q >> 5;
    A = xb + (size_t)mt * 128 * DD;
    B1 = rw1t; B3 = rw3t;
    H = Hr + (size_t)mt * 128 * FF;
  }
  int n0 = nt * 64;

  __shared__ __align__(16) unsigned short As[128 * 32];   // 8 frags x 1KB
  __shared__ __align__(16) unsigned short B1s[64 * 32];   // 4 frags
  __shared__ __align__(16) unsigned short B3s[64 * 32];

  int tid = threadIdx.x, l = tid & 63, w = tid >> 6;
  int wm = w >> 1, wn = w & 1;
  int fr = l & 15, fq = l >> 4;
  int lr = fr, lk = fq * 8;

  f32x4 acc1[4][2] = {};
  f32x4 acc3[4][2] = {};

  for (int kt = 0; kt < DD / 32; ++kt) {
    int k0 = kt * 32;
    __syncthreads();
    GLDS16(A + (size_t)(w * 16 + lr) * DD + k0 + lk, (char*)As + w * 1024);
    GLDS16(A + (size_t)((w + 4) * 16 + lr) * DD + k0 + lk, (char*)As + (w + 4) * 1024);
    GLDS16(B1 + (size_t)(n0 + w * 16 + lr) * DD + k0 + lk, (char*)B1s + w * 1024);
    GLDS16(B3 + (size_t)(n0 + w * 16 + lr) * DD + k0 + lk, (char*)B3s + w * 1024);
    __syncthreads();

    bf16x8 af[4], bf1[2], bf3[2];
#pragma unroll
    for (int mi = 0; mi < 4; ++mi)
      af[mi] = *(const bf16x8*)(As + (wm * 4 + mi) * 512 + l * 8);
#pragma unroll
    for (int ni = 0; ni < 2; ++ni) {
      bf1[ni] = *(const bf16x8*)(B1s + (wn * 2 + ni) * 512 + l * 8);
      bf3[ni] = *(const bf16x8*)(B3s + (wn * 2 + ni) * 512 + l * 8);
    }
#pragma unroll
    for (int mi = 0; mi < 4; ++mi)
#pragma unroll
      for (int ni = 0; ni < 2; ++ni) {
        acc1[mi][ni] = __builtin_amdgcn_mfma_f32_16x16x32_bf16(af[mi], bf1[ni], acc1[mi][ni], 0, 0, 0);
        acc3[mi][ni] = __builtin_amdgcn_mfma_f32_16x16x32_bf16(af[mi], bf3[ni], acc3[mi][ni], 0, 0, 0);
      }
  }

#pragma unroll
  for (int mi = 0; mi < 4; ++mi)
#pragma unroll
    for (int ni = 0; ni < 2; ++ni)
#pragma unroll
      for (int r = 0; r < 4; ++r) {
        int gm = wm * 64 + mi * 16 + fq * 4 + r;
        int gn = n0 + wn * 32 + ni * 16 + fr;
        float v1 = acc1[mi][ni][r], v3 = acc3[mi][ni][r];
        float h = v1 / (1.0f + __expf(-v1)) * v3;
        H[(size_t)gm * FF + gn] = f2bf(h);
      }
}

// ---------------- GEMM2: Y = H @ W2 ------------------------------
// 128x128 tile, BK=32, 4 waves, fragment-ordered LDS.
__global__ __launch_bounds__(256)
void gemm2_k(const unsigned short* __restrict__ He, const unsigned short* __restrict__ Hr,
             const unsigned short* __restrict__ w2t, const unsigned short* __restrict__ rw2t,
             unsigned short* __restrict__ Ye, unsigned short* __restrict__ Yr) {
  // 512 blocks, 64 per XCD.
  int lin = blockIdx.x;
  int work = (lin & 7) * 64 + (lin >> 3);
  const unsigned short *A, *B;
  unsigned short* Y;
  int nt;
  if (work < 256) {                // experts: ((e*8 + nt)*4 + mt)
    int mt = work & 3;
    int q = work >> 2;
    nt = q & 7;
    int e = q >> 3;
    A = He + (size_t)(e * 4 + mt) * 128 * FF;
    B = w2t + (size_t)e * DD * FF;
    Y = Ye + (size_t)(e * 4 + mt) * 128 * DD;
  } else {                         // residual: nt*32 + mt
    int q = work - 256;
    int mt = q & 31;
    nt = q >> 5;
    A = Hr + (size_t)mt * 128 * FF;
    B = rw2t;
    Y = Yr + (size_t)mt * 128 * DD;
  }
  int n0 = nt * 128;

  __shared__ __align__(16) unsigned short As[128 * 32];
  __shared__ __align__(16) unsigned short Bs[128 * 32];

  int tid = threadIdx.x, l = tid & 63, w = tid >> 6;
  int wm = w >> 1, wn = w & 1;
  int fr = l & 15, fq = l >> 4;
  int lr = fr, lk = fq * 8;

  f32x4 acc[4][4] = {};

  for (int kt = 0; kt < FF / 32; ++kt) {
    int k0 = kt * 32;
    __syncthreads();
    GLDS16(A + (size_t)(w * 16 + lr) * FF + k0 + lk, (char*)As + w * 1024);
    GLDS16(A + (size_t)((w + 4) * 16 + lr) * FF + k0 + lk, (char*)As + (w + 4) * 1024);
    GLDS16(B + (size_t)(n0 + w * 16 + lr) * FF + k0 + lk, (char*)Bs + w * 1024);
    GLDS16(B + (size_t)(n0 + (w + 4) * 16 + lr) * FF + k0 + lk, (char*)Bs + (w + 4) * 1024);
    __syncthreads();

    bf16x8 af[4], bfr[4];
#pragma unroll
    for (int mi = 0; mi < 4; ++mi)
      af[mi] = *(const bf16x8*)(As + (wm * 4 + mi) * 512 + l * 8);
#pragma unroll
    for (int ni = 0; ni < 4; ++ni)
      bfr[ni] = *(const bf16x8*)(Bs + (wn * 4 + ni) * 512 + l * 8);
#pragma unroll
    for (int mi = 0; mi < 4; ++mi)
#pragma unroll
      for (int ni = 0; ni < 4; ++ni)
        acc[mi][ni] = __builtin_amdgcn_mfma_f32_16x16x32_bf16(af[mi], bfr[ni], acc[mi][ni], 0, 0, 0);
  }

#pragma unroll
  for (int mi = 0; mi < 4; ++mi)
#pragma unroll
    for (int ni = 0; ni < 4; ++ni)
#pragma unroll
      for (int r = 0; r < 4; ++r) {
        int gm = wm * 64 + mi * 16 + fq * 4 + r;
        int gn = n0 + wn * 64 + ni * 16 + fr;
        Y[(size_t)gm * DD + gn] = f2bf(acc[mi][ni][r]);
      }
}

// ---------------- combine ----------------------------------------
__global__ void combine_k(const unsigned short* __restrict__ Ye, const unsigned short* __restrict__ Yr,
                          const int* __restrict__ idx, const int* __restrict__ slot,
                          const float* __restrict__ gatev, const float* __restrict__ coef,
                          float* __restrict__ out) {
  int t = blockIdx.x, tid = threadIdx.x;
  int d = tid * 4;
  float c0 = coef[t * 2], c1 = coef[t * 2 + 1];
  int s = slot[t];
  float g = gatev[t] * c0;
  us4 vr = *(const us4*)(Yr + (size_t)t * DD + d);
  float4 o;
  if (s >= 0) {
    us4 ve = *(const us4*)(Ye + ((size_t)idx[t] * CC + s) * DD + d);
    o.x = g * bf2f(ve.x) + c1 * bf2f(vr.x);
    o.y = g * bf2f(ve.y) + c1 * bf2f(vr.y);
    o.z = g * bf2f(ve.z) + c1 * bf2f(vr.z);
    o.w = g * bf2f(ve.w) + c1 * bf2f(vr.w);
  } else {
    o.x = c1 * bf2f(vr.x);
    o.y = c1 * bf2f(vr.y);
    o.z = c1 * bf2f(vr.z);
    o.w = c1 * bf2f(vr.w);
  }
  *(float4*)(out + (size_t)t * DD + d) = o;
}

// ---------------- launch -----------------------------------------
extern "C" void kernel_launch(void* const* d_in, const int* in_sizes, int n_in,
                              void* d_out, int out_size, void* d_ws, size_t ws_size,
                              hipStream_t stream) {
  const float* x   = (const float*)d_in[0];
  const float* wg  = (const float*)d_in[1];
  const float* w1  = (const float*)d_in[2];
  const float* w3  = (const float*)d_in[3];
  const float* w2  = (const float*)d_in[4];
  const float* rw1 = (const float*)d_in[5];
  const float* rw3 = (const float*)d_in[6];
  const float* rw2 = (const float*)d_in[7];
  const float* cw  = (const float*)d_in[8];
  const float* cbv = (const float*)d_in[9];
  float* out = (float*)d_out;

  char* ws = (char*)d_ws;
  size_t o = 0;
  auto alloc = [&](size_t bytes) -> char* {
    char* p = ws + o; o = (o + bytes + 255) & ~(size_t)255; return p;
  };
  unsigned short* w1t  = (unsigned short*)alloc((size_t)EE * FP * DD * 2);
  unsigned short* w3t  = (unsigned short*)alloc((size_t)EE * FP * DD * 2);
  unsigned short* w2t  = (unsigned short*)alloc((size_t)EE * DD * FF * 2);
  unsigned short* rw1t = (unsigned short*)alloc((size_t)FP * DD * 2);
  unsigned short* rw3t = (unsigned short*)alloc((size_t)FP * DD * 2);
  unsigned short* rw2t = (unsigned short*)alloc((size_t)DD * FF * 2);
  unsigned short* xb   = (unsigned short*)alloc((size_t)T_TOK * DD * 2);
  unsigned short* xe   = (unsigned short*)alloc((size_t)T_TOK * DD * 2);
  unsigned short* He   = (unsigned short*)alloc((size_t)T_TOK * FF * 2);
  unsigned short* Hr   = (unsigned short*)alloc((size_t)T_TOK * FF * 2);
  unsigned short* Ye   = (unsigned short*)alloc((size_t)T_TOK * DD * 2);
  unsigned short* Yr   = (unsigned short*)alloc((size_t)T_TOK * DD * 2);
  int*   idxp  = (int*)alloc(T_TOK * 4);
  float* gatev = (float*)alloc(T_TOK * 4);
  int*   slotp = (int*)alloc(T_TOK * 4);
  int*   tokp  = (int*)alloc(EE * CC * 4);
  float* coefp = (float*)alloc(T_TOK * 2 * 4);
  float* mep   = (float*)alloc(256);
  if (o > ws_size) return;

  // w1/w3: [E][1024][2752] -> [E][2752][1024] bf16 (FP-strided rows, pad never read)
  transpose_k<<<dim3(43, 16, EE), 256, 0, stream>>>(w1, w1t, DD, FF, (long)DD * FF, (long)FP * DD);
  transpose_k<<<dim3(43, 16, EE), 256, 0, stream>>>(w3, w3t, DD, FF, (long)DD * FF, (long)FP * DD);
  // w2: [E][2752][1024] -> [E][1024][2752] bf16
  transpose_k<<<dim3(16, 43, EE), 256, 0, stream>>>(w2, w2t, FF, DD, (long)FF * DD, (long)DD * FF);
  transpose_k<<<dim3(43, 16, 1), 256, 0, stream>>>(rw1, rw1t, DD, FF, 0, 0);
  transpose_k<<<dim3(43, 16, 1), 256, 0, stream>>>(rw3, rw3t, DD, FF, 0, 0);
  transpose_k<<<dim3(16, 43, 1), 256, 0, stream>>>(rw2, rw2t, FF, DD, 0, 0);

  zero_me_k<<<1, 64, 0, stream>>>(mep);
  gate_k<<<T_TOK / 4, 256, 0, stream>>>(x, wg, cw, cbv, idxp, gatev, coefp, mep);
  scan_k<<<1, 512, 0, stream>>>(idxp, mep, slotp, tokp, out + (size_t)T_TOK * DD);
  gather_k<<<2 * T_TOK, 256, 0, stream>>>(x, tokp, xb, xe);
  gemm1_k<<<2752, 256, 0, stream>>>(xe, xb, w1t, w3t, rw1t, rw3t, He, Hr);
  gemm2_k<<<512, 256, 0, stream>>>(He, Hr, w2t, rw2t, Ye, Yr);
  combine_k<<<T_TOK, 256, 0, stream>>>(Ye, Yr, idxp, slotp, gatev, coefp, out);
}

// Round 3
// 352.649 us; speedup vs baseline: 1.2289x; 1.2289x over previous
//
#include <hip/hip_runtime.h>
#include <hip/hip_bf16.h>
#include <stdint.h>

#define T_TOK 4096
#define DD 1024
#define EE 8
#define CC 512
#define FF 2752
#define FP 2816

typedef __attribute__((ext_vector_type(8))) short bf16x8;
typedef __attribute__((ext_vector_type(4))) float f32x4;
typedef __attribute__((ext_vector_type(4))) unsigned short us4;

__device__ __forceinline__ float bf2f(unsigned short u) {
  union { float f; unsigned int i; } v; v.i = ((unsigned int)u) << 16; return v.f;
}
__device__ __forceinline__ unsigned short f2bf(float f) {
  union { float f; unsigned int i; } v; v.f = f;
  unsigned int r = v.i + 0x7fffu + ((v.i >> 16) & 1u);
  return (unsigned short)(r >> 16);
}

#define GLDS16(g, l) __builtin_amdgcn_global_load_lds( \
    (const __attribute__((address_space(1))) void*)(g), \
    (__attribute__((address_space(3))) void*)(l), 16, 0, 0)

// ---------------- weight transpose + f32->bf16 -------------------
__global__ __launch_bounds__(256)
void transpose_k(const float* __restrict__ in, unsigned short* __restrict__ out,
                 int R, int C, long inStride, long outStride) {
  __shared__ unsigned short sm[64][68];
  int b = blockIdx.z;
  in += (long)b * inStride;
  out += (long)b * outStride;
  int cb = blockIdx.x * 64, rb = blockIdx.y * 64;
  int t = threadIdx.x;
  int rr = t >> 4, c4 = (t & 15) * 4;
#pragma unroll
  for (int i = 0; i < 4; ++i) {
    int r = rr + i * 16;
    float4 v = *(const float4*)(in + (long)(rb + r) * C + cb + c4);
    us4 o; o.x = f2bf(v.x); o.y = f2bf(v.y); o.z = f2bf(v.z); o.w = f2bf(v.w);
    *(us4*)&sm[r][c4] = o;
  }
  __syncthreads();
  int r4 = (t & 15) * 4, cc = t >> 4;
#pragma unroll
  for (int i = 0; i < 4; ++i) {
    int c = cc + i * 16;
    us4 o;
    o.x = sm[r4 + 0][c]; o.y = sm[r4 + 1][c];
    o.z = sm[r4 + 2][c]; o.w = sm[r4 + 3][c];
    *(us4*)(out + (long)(cb + c) * R + rb + r4) = o;
  }
}

__global__ void zero_me_k(float* me) { if (threadIdx.x < EE) me[threadIdx.x] = 0.0f; }

// ---------------- gating ----------------
__global__ void gate_k(const float* __restrict__ x, const float* __restrict__ wg,
                       const float* __restrict__ cw, const float* __restrict__ cbv,
                       int* __restrict__ idx, float* __restrict__ gatev,
                       float* __restrict__ coef, float* __restrict__ me_sum) {
  int tid = threadIdx.x, lane = tid & 63, wv = tid >> 6;
  int t = blockIdx.x * 4 + wv;
  const float* xr = x + (long)t * DD;
  float acc[EE] = {0,0,0,0,0,0,0,0};
  float c0 = 0.0f, c1 = 0.0f;
  for (int d = lane; d < DD; d += 64) {
    float xv = xr[d];
#pragma unroll
    for (int e = 0; e < EE; ++e) acc[e] += xv * wg[d * EE + e];
    c0 += xv * cw[d * 2 + 0];
    c1 += xv * cw[d * 2 + 1];
  }
#pragma unroll
  for (int o = 32; o > 0; o >>= 1) {
#pragma unroll
    for (int e = 0; e < EE; ++e) acc[e] += __shfl_xor(acc[e], o);
    c0 += __shfl_xor(c0, o);
    c1 += __shfl_xor(c1, o);
  }
  __shared__ float sme[EE];
  if (tid < EE) sme[tid] = 0.0f;
  __syncthreads();
  if (lane == 0) {
    float m = acc[0]; int am = 0;
#pragma unroll
    for (int e = 1; e < EE; ++e) if (acc[e] > m) { m = acc[e]; am = e; }
    float g[EE]; float s = 0.0f;
#pragma unroll
    for (int e = 0; e < EE; ++e) { g[e] = __expf(acc[e] - m); s += g[e]; }
    float inv = 1.0f / s;
    idx[t] = am;
    gatev[t] = g[am] * inv;
#pragma unroll
    for (int e = 0; e < EE; ++e) atomicAdd(&sme[e], g[e] * inv);
    float l0 = c0 + cbv[0], l1 = c1 + cbv[1];
    float mm = fmaxf(l0, l1);
    float e0 = __expf(l0 - mm), e1 = __expf(l1 - mm);
    float is = 1.0f / (e0 + e1);
    coef[t * 2 + 0] = e0 * is;
    coef[t * 2 + 1] = e1 * is;
  }
  __syncthreads();
  if (tid < EE) atomicAdd(&me_sum[tid], sme[tid]);
}

// ---------------- capacity scan ----------------
__global__ void scan_k(const int* __restrict__ idx, const float* __restrict__ me_sum,
                       int* __restrict__ slot, int* __restrict__ tok,
                       float* __restrict__ out_tail) {
  __shared__ int sidx[T_TOK];
  __shared__ int counts[EE];
  int tid = threadIdx.x;
  for (int i = tid; i < T_TOK; i += 512) sidx[i] = idx[i];
  __syncthreads();
  int e = tid >> 6, lane = tid & 63;
  int base = 0;
  for (int it = 0; it < T_TOK / 64; ++it) {
    int t = it * 64 + lane;
    bool f = (sidx[t] == e);
    unsigned long long m = __ballot(f);
    if (f) {
      int loc = base + __popcll(m & ((1ull << lane) - 1ull));
      slot[t] = (loc < CC) ? loc : -1;
      if (loc < CC) tok[e * CC + loc] = t;
    }
    base += __popcll(m);
  }
  if (lane == 0) counts[e] = base;
  __syncthreads();
  int filled = min(counts[e], CC);
  for (int c = filled + lane; c < CC; c += 64) tok[e * CC + c] = -1;
  if (tid == 0) {
    float la = 0.0f;
    for (int i = 0; i < EE; ++i) la += me_sum[i] * (float)counts[i];
    la *= (float)EE / ((float)T_TOK * (float)T_TOK);
    out_tail[0] = la;
    for (int i = 0; i < EE; ++i) out_tail[1 + i] = (float)counts[i];
  }
}

// ---------------- gather + bf16 convert ----------------
__global__ void gather_k(const float* __restrict__ x, const int* __restrict__ tok,
                         unsigned short* __restrict__ xb, unsigned short* __restrict__ xe) {
  int r = blockIdx.x, tid = threadIdx.x;
  int d = tid * 4;
  if (r < T_TOK) {
    float4 v = *(const float4*)(x + (long)r * DD + d);
    us4 o; o.x = f2bf(v.x); o.y = f2bf(v.y); o.z = f2bf(v.z); o.w = f2bf(v.w);
    *(us4*)(xb + (long)r * DD + d) = o;
  } else {
    int s = r - T_TOK;
    int t = tok[s];
    us4 o = {0, 0, 0, 0};
    if (t >= 0) {
      float4 v = *(const float4*)(x + (long)t * DD + d);
      o.x = f2bf(v.x); o.y = f2bf(v.y); o.z = f2bf(v.z); o.w = f2bf(v.w);
    }
    *(us4*)(xe + (long)s * DD + d) = o;
  }
}

// Staging swizzle: stage-lane l fetches row (l>>2), 16B-chunk ((l&3)^((l>>3)&3))
// of a 16-row x 64B block -> LDS linear. Read side: lane (fr,fq) reads LDS byte
// fr*64 + (fq^((fr>>1)&3))*16. Global segments stay 64B-contiguous per row
// (coalescing = linear), LDS read banks balanced (no 8-way conflict).
#define STG_CHUNK(l) (((l & 3) ^ ((l >> 3) & 3)) * 8)   // element offset
#define RD_OFF(fr, fq) ((fr) * 32 + (((fq) ^ (((fr) >> 1) & 3)) * 8))  // element offset

// ---------------- GEMM1: H = silu(A@W1)*(A@W3) -------------------
__global__ __launch_bounds__(256)
void gemm1_k(const unsigned short* __restrict__ xe, const unsigned short* __restrict__ xb,
             const unsigned short* __restrict__ w1t, const unsigned short* __restrict__ w3t,
             const unsigned short* __restrict__ rw1t, const unsigned short* __restrict__ rw3t,
             unsigned short* __restrict__ He, unsigned short* __restrict__ Hr) {
  int lin = blockIdx.x;
  int work = (lin & 7) * 344 + (lin >> 3);
  const unsigned short *A, *B1, *B3;
  unsigned short* H;
  int nt;
  if (work < 1376) {               // experts: ((e*43 + nt)*4 + mt)
    int mt = work & 3;
    int q = work >> 2;
    nt = q % 43;
    int e = q / 43;
    A = xe + (size_t)(e * 4 + mt) * 128 * DD;
    B1 = w1t + (size_t)e * FP * DD;
    B3 = w3t + (size_t)e * FP * DD;
    H = He + (size_t)(e * 4 + mt) * 128 * FF;
  } else {                         // residual: nt*32 + mt
    int q = work - 1376;
    int mt = q & 31;
    nt = q >> 5;
    A = xb + (size_t)mt * 128 * DD;
    B1 = rw1t; B3 = rw3t;
    H = Hr + (size_t)mt * 128 * FF;
  }
  int n0 = nt * 64;

  __shared__ __align__(16) unsigned short As[128 * 32];
  __shared__ __align__(16) unsigned short B1s[64 * 32];
  __shared__ __align__(16) unsigned short B3s[64 * 32];

  int tid = threadIdx.x, l = tid & 63, w = tid >> 6;
  int wm = w >> 1, wn = w & 1;
  int fr = l & 15, fq = l >> 4;
  int srow = l >> 2, soff = STG_CHUNK(l);   // staging: row-grouped, chunk-swizzled

  f32x4 acc1[4][2] = {};
  f32x4 acc3[4][2] = {};

  for (int kt = 0; kt < DD / 32; ++kt) {
    int k0 = kt * 32;
    __syncthreads();
    GLDS16(A + (size_t)(w * 16 + srow) * DD + k0 + soff, (char*)As + w * 1024);
    GLDS16(A + (size_t)((w + 4) * 16 + srow) * DD + k0 + soff, (char*)As + (w + 4) * 1024);
    GLDS16(B1 + (size_t)(n0 + w * 16 + srow) * DD + k0 + soff, (char*)B1s + w * 1024);
    GLDS16(B3 + (size_t)(n0 + w * 16 + srow) * DD + k0 + soff, (char*)B3s + w * 1024);
    __syncthreads();

    bf16x8 af[4], bf1[2], bf3[2];
#pragma unroll
    for (int mi = 0; mi < 4; ++mi)
      af[mi] = *(const bf16x8*)(As + (wm * 4 + mi) * 512 + RD_OFF(fr, fq));
#pragma unroll
    for (int ni = 0; ni < 2; ++ni) {
      bf1[ni] = *(const bf16x8*)(B1s + (wn * 2 + ni) * 512 + RD_OFF(fr, fq));
      bf3[ni] = *(const bf16x8*)(B3s + (wn * 2 + ni) * 512 + RD_OFF(fr, fq));
    }
#pragma unroll
    for (int mi = 0; mi < 4; ++mi)
#pragma unroll
      for (int ni = 0; ni < 2; ++ni) {
        acc1[mi][ni] = __builtin_amdgcn_mfma_f32_16x16x32_bf16(af[mi], bf1[ni], acc1[mi][ni], 0, 0, 0);
        acc3[mi][ni] = __builtin_amdgcn_mfma_f32_16x16x32_bf16(af[mi], bf3[ni], acc3[mi][ni], 0, 0, 0);
      }
  }

#pragma unroll
  for (int mi = 0; mi < 4; ++mi)
#pragma unroll
    for (int ni = 0; ni < 2; ++ni)
#pragma unroll
      for (int r = 0; r < 4; ++r) {
        int gm = wm * 64 + mi * 16 + fq * 4 + r;
        int gn = n0 + wn * 32 + ni * 16 + fr;
        float v1 = acc1[mi][ni][r], v3 = acc3[mi][ni][r];
        float h = v1 / (1.0f + __expf(-v1)) * v3;
        H[(size_t)gm * FF + gn] = f2bf(h);
      }
}

// ---------------- GEMM2: Y = H @ W2 ------------------------------
__global__ __launch_bounds__(256)
void gemm2_k(const unsigned short* __restrict__ He, const unsigned short* __restrict__ Hr,
             const unsigned short* __restrict__ w2t, const unsigned short* __restrict__ rw2t,
             unsigned short* __restrict__ Ye, unsigned short* __restrict__ Yr) {
  int lin = blockIdx.x;
  int work = (lin & 7) * 64 + (lin >> 3);
  const unsigned short *A, *B;
  unsigned short* Y;
  int nt;
  if (work < 256) {                // experts: ((e*8 + nt)*4 + mt)
    int mt = work & 3;
    int q = work >> 2;
    nt = q & 7;
    int e = q >> 3;
    A = He + (size_t)(e * 4 + mt) * 128 * FF;
    B = w2t + (size_t)e * DD * FF;
    Y = Ye + (size_t)(e * 4 + mt) * 128 * DD;
  } else {                         // residual: nt*32 + mt
    int q = work - 256;
    int mt = q & 31;
    nt = q >> 5;
    A = Hr + (size_t)mt * 128 * FF;
    B = rw2t;
    Y = Yr + (size_t)mt * 128 * DD;
  }
  int n0 = nt * 128;

  __shared__ __align__(16) unsigned short As[128 * 32];
  __shared__ __align__(16) unsigned short Bs[128 * 32];

  int tid = threadIdx.x, l = tid & 63, w = tid >> 6;
  int wm = w >> 1, wn = w & 1;
  int fr = l & 15, fq = l >> 4;
  int srow = l >> 2, soff = STG_CHUNK(l);

  f32x4 acc[4][4] = {};

  for (int kt = 0; kt < FF / 32; ++kt) {
    int k0 = kt * 32;
    __syncthreads();
    GLDS16(A + (size_t)(w * 16 + srow) * FF + k0 + soff, (char*)As + w * 1024);
    GLDS16(A + (size_t)((w + 4) * 16 + srow) * FF + k0 + soff, (char*)As + (w + 4) * 1024);
    GLDS16(B + (size_t)(n0 + w * 16 + srow) * FF + k0 + soff, (char*)Bs + w * 1024);
    GLDS16(B + (size_t)(n0 + (w + 4) * 16 + srow) * FF + k0 + soff, (char*)Bs + (w + 4) * 1024);
    __syncthreads();

    bf16x8 af[4], bfr[4];
#pragma unroll
    for (int mi = 0; mi < 4; ++mi)
      af[mi] = *(const bf16x8*)(As + (wm * 4 + mi) * 512 + RD_OFF(fr, fq));
#pragma unroll
    for (int ni = 0; ni < 4; ++ni)
      bfr[ni] = *(const bf16x8*)(Bs + (wn * 4 + ni) * 512 + RD_OFF(fr, fq));
#pragma unroll
    for (int mi = 0; mi < 4; ++mi)
#pragma unroll
      for (int ni = 0; ni < 4; ++ni)
        acc[mi][ni] = __builtin_amdgcn_mfma_f32_16x16x32_bf16(af[mi], bfr[ni], acc[mi][ni], 0, 0, 0);
  }

#pragma unroll
  for (int mi = 0; mi < 4; ++mi)
#pragma unroll
    for (int ni = 0; ni < 4; ++ni)
#pragma unroll
      for (int r = 0; r < 4; ++r) {
        int gm = wm * 64 + mi * 16 + fq * 4 + r;
        int gn = n0 + wn * 64 + ni * 16 + fr;
        Y[(size_t)gm * DD + gn] = f2bf(acc[mi][ni][r]);
      }
}

// ---------------- combine ----------------------------------------
__global__ void combine_k(const unsigned short* __restrict__ Ye, const unsigned short* __restrict__ Yr,
                          const int* __restrict__ idx, const int* __restrict__ slot,
                          const float* __restrict__ gatev, const float* __restrict__ coef,
                          float* __restrict__ out) {
  int t = blockIdx.x, tid = threadIdx.x;
  int d = tid * 4;
  float c0 = coef[t * 2], c1 = coef[t * 2 + 1];
  int s = slot[t];
  float g = gatev[t] * c0;
  us4 vr = *(const us4*)(Yr + (size_t)t * DD + d);
  float4 o;
  if (s >= 0) {
    us4 ve = *(const us4*)(Ye + ((size_t)idx[t] * CC + s) * DD + d);
    o.x = g * bf2f(ve.x) + c1 * bf2f(vr.x);
    o.y = g * bf2f(ve.y) + c1 * bf2f(vr.y);
    o.z = g * bf2f(ve.z) + c1 * bf2f(vr.z);
    o.w = g * bf2f(ve.w) + c1 * bf2f(vr.w);
  } else {
    o.x = c1 * bf2f(vr.x);
    o.y = c1 * bf2f(vr.y);
    o.z = c1 * bf2f(vr.z);
    o.w = c1 * bf2f(vr.w);
  }
  *(float4*)(out + (size_t)t * DD + d) = o;
}

// ---------------- launch -----------------------------------------
extern "C" void kernel_launch(void* const* d_in, const int* in_sizes, int n_in,
                              void* d_out, int out_size, void* d_ws, size_t ws_size,
                              hipStream_t stream) {
  const float* x   = (const float*)d_in[0];
  const float* wg  = (const float*)d_in[1];
  const float* w1  = (const float*)d_in[2];
  const float* w3  = (const float*)d_in[3];
  const float* w2  = (const float*)d_in[4];
  const float* rw1 = (const float*)d_in[5];
  const float* rw3 = (const float*)d_in[6];
  const float* rw2 = (const float*)d_in[7];
  const float* cw  = (const float*)d_in[8];
  const float* cbv = (const float*)d_in[9];
  float* out = (float*)d_out;

  char* ws = (char*)d_ws;
  size_t o = 0;
  auto alloc = [&](size_t bytes) -> char* {
    char* p = ws + o; o = (o + bytes + 255) & ~(size_t)255; return p;
  };
  unsigned short* w1t  = (unsigned short*)alloc((size_t)EE * FP * DD * 2);
  unsigned short* w3t  = (unsigned short*)alloc((size_t)EE * FP * DD * 2);
  unsigned short* w2t  = (unsigned short*)alloc((size_t)EE * DD * FF * 2);
  unsigned short* rw1t = (unsigned short*)alloc((size_t)FP * DD * 2);
  unsigned short* rw3t = (unsigned short*)alloc((size_t)FP * DD * 2);
  unsigned short* rw2t = (unsigned short*)alloc((size_t)DD * FF * 2);
  unsigned short* xb   = (unsigned short*)alloc((size_t)T_TOK * DD * 2);
  unsigned short* xe   = (unsigned short*)alloc((size_t)T_TOK * DD * 2);
  unsigned short* He   = (unsigned short*)alloc((size_t)T_TOK * FF * 2);
  unsigned short* Hr   = (unsigned short*)alloc((size_t)T_TOK * FF * 2);
  unsigned short* Ye   = (unsigned short*)alloc((size_t)T_TOK * DD * 2);
  unsigned short* Yr   = (unsigned short*)alloc((size_t)T_TOK * DD * 2);
  int*   idxp  = (int*)alloc(T_TOK * 4);
  float* gatev = (float*)alloc(T_TOK * 4);
  int*   slotp = (int*)alloc(T_TOK * 4);
  int*   tokp  = (int*)alloc(EE * CC * 4);
  float* coefp = (float*)alloc(T_TOK * 2 * 4);
  float* mep   = (float*)alloc(256);
  if (o > ws_size) return;

  transpose_k<<<dim3(43, 16, EE), 256, 0, stream>>>(w1, w1t, DD, FF, (long)DD * FF, (long)FP * DD);
  transpose_k<<<dim3(43, 16, EE), 256, 0, stream>>>(w3, w3t, DD, FF, (long)DD * FF, (long)FP * DD);
  transpose_k<<<dim3(16, 43, EE), 256, 0, stream>>>(w2, w2t, FF, DD, (long)FF * DD, (long)DD * FF);
  transpose_k<<<dim3(43, 16, 1), 256, 0, stream>>>(rw1, rw1t, DD, FF, 0, 0);
  transpose_k<<<dim3(43, 16, 1), 256, 0, stream>>>(rw3, rw3t, DD, FF, 0, 0);
  transpose_k<<<dim3(16, 43, 1), 256, 0, stream>>>(rw2, rw2t, FF, DD, 0, 0);

  zero_me_k<<<1, 64, 0, stream>>>(mep);
  gate_k<<<T_TOK / 4, 256, 0, stream>>>(x, wg, cw, cbv, idxp, gatev, coefp, mep);
  scan_k<<<1, 512, 0, stream>>>(idxp, mep, slotp, tokp, out + (size_t)T_TOK * DD);
  gather_k<<<2 * T_TOK, 256, 0, stream>>>(x, tokp, xb, xe);
  gemm1_k<<<2752, 256, 0, stream>>>(xe, xb, w1t, w3t, rw1t, rw3t, He, Hr);
  gemm2_k<<<512, 256, 0, stream>>>(He, Hr, w2t, rw2t, Ye, Yr);
  combine_k<<<T_TOK, 256, 0, stream>>>(Ye, Yr, idxp, slotp, gatev, coefp, out);
}